// Round 8
// baseline (193.471 us; speedup 1.0000x reference)
//
#include <hip/hip_runtime.h>
#include <hip/hip_bf16.h>

#define B_ 16
#define S_ 512
#define E_ 512
#define H_ 8
#define D_ 64

typedef __hip_bfloat16 bf16;
typedef unsigned short u16;
typedef __attribute__((ext_vector_type(8))) short short8;
typedef __attribute__((ext_vector_type(4))) float floatx4;

__device__ __forceinline__ u16 f2b(float x) {
    bf16 h = __float2bfloat16(x);
    return *reinterpret_cast<u16*>(&h);
}
__device__ __forceinline__ short8 ld8(const u16* p) { return *(const short8*)p; }

// quad_perm DPP xor within groups of 4 lanes (pure VALU, no LDS)
template<int CTRL>
__device__ __forceinline__ float qperm(float x) {
    return __builtin_bit_cast(float,
        __builtin_amdgcn_update_dpp(0, __builtin_bit_cast(int, x), CTRL, 0xF, 0xF, true));
}

#define PROJ_ROW_BLOCKS 3072   // 3 proj x 65536 rows / 64 rows-per-block

// ---------------------------------------------------------------------------
// Kernel A: quantum projections (closed-form VQC), quad-per-row layout.
// 4 lanes own one (b,s,h) row; lane j handles d in [16j,16j+16).
// Q/K/V written bf16 in (B,H,S,D).  Tail blocks convert Wo fp32->bf16.
// ---------------------------------------------------------------------------
__global__ __launch_bounds__(256) void proj_kernel(
    const float* __restrict__ q_in, const float* __restrict__ k_in, const float* __restrict__ v_in,
    const float* __restrict__ Wq_in, const float* __restrict__ bq_in,
    const float* __restrict__ Wk_in, const float* __restrict__ bk_in,
    const float* __restrict__ Wv_in, const float* __restrict__ bv_in,
    const float* __restrict__ wvq, const float* __restrict__ wvk, const float* __restrict__ wvv,
    const float* __restrict__ Wq, const float* __restrict__ bq,
    const float* __restrict__ Wk, const float* __restrict__ bk,
    const float* __restrict__ Wv, const float* __restrict__ bv,
    const float* __restrict__ Wo, u16* __restrict__ Wb,
    u16* __restrict__ Qb, u16* __restrict__ Kb, u16* __restrict__ Vb)
{
    if (blockIdx.x >= PROJ_ROW_BLOCKS) {
        // fused Wo fp32 -> bf16 (524288 elems, 256 blocks x 256 threads x 8)
        const int i = ((blockIdx.x - PROJ_ROW_BLOCKS) * 256 + threadIdx.x) * 8;
        const float4 a = *(const float4*)&Wo[i];
        const float4 b4 = *(const float4*)&Wo[i + 4];
        u16 tmp[8] __attribute__((aligned(16)));
        tmp[0] = f2b(a.x); tmp[1] = f2b(a.y); tmp[2] = f2b(a.z); tmp[3] = f2b(a.w);
        tmp[4] = f2b(b4.x); tmp[5] = f2b(b4.y); tmp[6] = f2b(b4.z); tmp[7] = f2b(b4.w);
        *(short8*)&Wb[i] = *(short8*)tmp;
        return;
    }

    __shared__ __align__(16) float sWin[256];    // [q][d]  (4 x 64)
    __shared__ __align__(16) float sWout[256];   // [d][q]  (64 x 4)
    __shared__ __align__(16) float sbout[64];
    __shared__ float4 sbw;                       // bin + wv (aligned)

    const int t = threadIdx.x;
    const int p = blockIdx.x >> 10;           // projection 0/1/2

    const float *X, *Win, *bin, *wv, *Wout, *bout;
    u16* dst;
    if (p == 0)      { X = q_in; Win = Wq_in; bin = bq_in; wv = wvq; Wout = Wq; bout = bq; dst = Qb; }
    else if (p == 1) { X = k_in; Win = Wk_in; bin = bk_in; wv = wvk; Wout = Wk; bout = bk; dst = Kb; }
    else             { X = v_in; Win = Wv_in; bin = bv_in; wv = wvv; Wout = Wv; bout = bv; dst = Vb; }

    sWin[t] = Win[t];
    sWout[t] = Wout[t];
    if (t < 64) sbout[t] = bout[t];
    if (t == 0) sbw = make_float4(bin[0] + wv[0], bin[1] + wv[1],
                                  bin[2] + wv[2], bin[3] + wv[3]);
    __syncthreads();

    const int j = t & 3;                       // d-quarter within row
    const int m = (blockIdx.x & 1023) * 64 + (t >> 2);   // row = b*4096 + s*8 + h
    const int d0 = j * 16;

    // ---- dot phase: part[q] over my 16 d's, then quad reduce via DPP
    const float* xp = X + (size_t)m * 64 + d0;
    float4 xv[4];
#pragma unroll
    for (int i = 0; i < 4; ++i) xv[i] = *(const float4*)(xp + i * 4);

    float part[4] = {0.f, 0.f, 0.f, 0.f};
#pragma unroll
    for (int i = 0; i < 4; ++i) {
#pragma unroll
        for (int q = 0; q < 4; ++q) {
            const float4 w4 = *(const float4*)&sWin[q * 64 + d0 + i * 4];
            part[q] = fmaf(xv[i].x, w4.x, fmaf(xv[i].y, w4.y,
                      fmaf(xv[i].z, w4.z, fmaf(xv[i].w, w4.w, part[q]))));
        }
    }
#pragma unroll
    for (int q = 0; q < 4; ++q) {
        part[q] += qperm<0xB1>(part[q]);   // xor 1
        part[q] += qperm<0x4E>(part[q]);   // xor 2
    }

    const float4 bw = sbw;
    const float c0 = __cosf(part[0] + bw.x);
    const float c1 = __cosf(part[1] + bw.y);
    const float c2 = __cosf(part[2] + bw.z);
    const float c3 = __cosf(part[3] + bw.w);
    const float tt = c2 * c3;
    const float z1 = c0 * c1;
    const float z0 = c1 * tt;
    const float z2 = z1 * c2;
    const float z3 = z1 * tt;

    // ---- output phase: my 16 d's
    const int b = m >> 12, s = (m >> 3) & 511, h = m & 7;
    u16* op = dst + ((size_t)(b * 4096 + h * 512 + s)) * 64 + d0;

    u16 tmp[16] __attribute__((aligned(16)));
#pragma unroll
    for (int d = 0; d < 16; ++d) {
        const float4 wo = *(const float4*)&sWout[(d0 + d) * 4];
        const float o = fmaf(z0, wo.x, fmaf(z1, wo.y,
                        fmaf(z2, wo.z, fmaf(z3, wo.w, sbout[d0 + d]))));
        tmp[d] = f2b(o);
    }
    *(short8*)op = *(short8*)tmp;
    *(short8*)(op + 8) = *(short8*)(tmp + 8);
}

// ---------------------------------------------------------------------------
// Kernel B: flash MFMA attention, NO max-tracking (softmax arg = S/32, tiny).
// Block = 64 q-rows of one (b,h), 4 waves x 16 rows, 8 chunks of 64 k-pos.
// DOUBLE-BUFFERED K/V staging: one barrier per chunk; global prefetch loads
// issue before the barrier so their latency hides under the compute phase.
// ---------------------------------------------------------------------------
__global__ __launch_bounds__(256) void attn_kernel(
    const u16* __restrict__ Qb, const u16* __restrict__ Kb, const u16* __restrict__ Vb,
    u16* __restrict__ Ob)
{
    __shared__ __align__(16) u16 Ks[2][64][72];     // [buf][kpos][d]
    __shared__ __align__(16) u16 Vt[2][64][72];     // [buf][d][kpos] (transposed)
    __shared__ __align__(16) u16 Ps[4][16][72];     // per-wave P [qrow][kpos]

    const int t = threadIdx.x, lane = t & 63, w = t >> 6;
    const int bh = blockIdx.x >> 3;
    const int q0 = (blockIdx.x & 7) * 64;
    const int b = bh >> 3, h = bh & 7;

    const u16* Qp = Qb + (size_t)bh * (S_ * D_) + (size_t)q0 * D_;
    const u16* Kp = Kb + (size_t)bh * (S_ * D_);
    const u16* Vp = Vb + (size_t)bh * (S_ * D_);

    const int nl = lane & 15;           // n-index within 16x16 tile
    const int kg = (lane >> 4) * 8;     // k-group offset

    // Q fragments straight from global (coalesced 16B)
    const short8 qa0 = ld8(&Qp[(w * 16 + nl) * 64 + kg]);
    const short8 qa1 = ld8(&Qp[(w * 16 + nl) * 64 + kg + 32]);

    floatx4 of[4];
    float l_run[4] = {0.f, 0.f, 0.f, 0.f};
#pragma unroll
    for (int nt = 0; nt < 4; ++nt) of[nt] = 0.f;

    // staging coords
    const int rK = t & 63, cK = (t >> 6) * 8;            // K: 2 vectors (cK, cK+32)
    const int vr0 = (t & 31) * 2, vc = (t >> 5) * 8;     // V: rows vr0, vr0+1 at col vc

    // load chunk 0 and write into buf 0 (no barrier needed until loop entry)
    {
        short8 kA = ld8(&Kp[rK * 64 + cK]);
        short8 kB = ld8(&Kp[rK * 64 + cK + 32]);
        short8 vA = ld8(&Vp[vr0 * 64 + vc]);
        short8 vB = ld8(&Vp[(vr0 + 1) * 64 + vc]);
        *(short8*)&Ks[0][rK][cK] = kA;
        *(short8*)&Ks[0][rK][cK + 32] = kB;
#pragma unroll
        for (int jj = 0; jj < 8; ++jj) {
            const unsigned pack = (u16)((short*)&vA)[jj] |
                                  ((unsigned)(u16)((short*)&vB)[jj] << 16);
            *(unsigned*)&Vt[0][vc + jj][vr0] = pack;
        }
    }

    for (int ch = 0; ch < 8; ++ch) {
        const int cur = ch & 1, nxt = cur ^ 1;
        // issue next chunk's global loads (latency covered by compute below)
        short8 kA, kB, vA, vB;
        if (ch < 7) {
            const int nb = (ch + 1) * 64;
            kA = ld8(&Kp[(nb + rK) * 64 + cK]);
            kB = ld8(&Kp[(nb + rK) * 64 + cK + 32]);
            vA = ld8(&Vp[(nb + vr0) * 64 + vc]);
            vB = ld8(&Vp[(nb + vr0 + 1) * 64 + vc]);
        }
        __syncthreads();    // buf[cur] fully written by all waves

        // S = Q K^T
        floatx4 sf[4];
#pragma unroll
        for (int nt = 0; nt < 4; ++nt) sf[nt] = 0.f;
#pragma unroll
        for (int nt = 0; nt < 4; ++nt) {
            sf[nt] = __builtin_amdgcn_mfma_f32_16x16x32_bf16(qa0, ld8(&Ks[cur][nt * 16 + nl][kg]), sf[nt], 0, 0, 0);
            sf[nt] = __builtin_amdgcn_mfma_f32_16x16x32_bf16(qa1, ld8(&Ks[cur][nt * 16 + nl][kg + 32]), sf[nt], 0, 0, 0);
        }

        // P = exp(S/32), accumulate row-sum partials in registers
        const int prow = (lane >> 4) * 4;
#pragma unroll
        for (int nt = 0; nt < 4; ++nt) {
#pragma unroll
            for (int r = 0; r < 4; ++r) {
                const float pv = __expf(sf[nt][r] * 0.03125f);
                l_run[r] += pv;
                Ps[w][prow + r][nt * 16 + nl] = f2b(pv);
            }
        }

        // O += P V (same-wave LDS round-trip)
        const short8 pa0 = ld8(&Ps[w][nl][kg]);
        const short8 pa1 = ld8(&Ps[w][nl][kg + 32]);
#pragma unroll
        for (int nt = 0; nt < 4; ++nt) {
            of[nt] = __builtin_amdgcn_mfma_f32_16x16x32_bf16(pa0, ld8(&Vt[cur][nt * 16 + nl][kg]), of[nt], 0, 0, 0);
            of[nt] = __builtin_amdgcn_mfma_f32_16x16x32_bf16(pa1, ld8(&Vt[cur][nt * 16 + nl][kg + 32]), of[nt], 0, 0, 0);
        }

        // write prefetched chunk into the other buffer (safe: all waves'
        // reads of buf[nxt] finished before this iteration's barrier)
        if (ch < 7) {
            *(short8*)&Ks[nxt][rK][cK] = kA;
            *(short8*)&Ks[nxt][rK][cK + 32] = kB;
#pragma unroll
            for (int jj = 0; jj < 8; ++jj) {
                const unsigned pack = (u16)((short*)&vA)[jj] |
                                      ((unsigned)(u16)((short*)&vB)[jj] << 16);
                *(unsigned*)&Vt[nxt][vc + jj][vr0] = pack;
            }
        }
    }

    // final row-sum reduce (16 lanes share a row) + store O/l bf16 to (B,S,E)
    float inv[4];
#pragma unroll
    for (int r = 0; r < 4; ++r) {
        float sum = l_run[r];
#pragma unroll
        for (int off = 1; off < 16; off <<= 1) sum += __shfl_xor(sum, off, 64);
        inv[r] = 1.0f / sum;
    }
    const int srow = q0 + w * 16 + (lane >> 4) * 4;
#pragma unroll
    for (int r = 0; r < 4; ++r) {
        const size_t base = ((size_t)(b * S_ + srow + r)) * E_ + h * 64 + nl;
#pragma unroll
        for (int nt = 0; nt < 4; ++nt)
            Ob[base + nt * 16] = f2b(of[nt][r] * inv[r]);
    }
}

// ---------------------------------------------------------------------------
// Kernel C: out = [Qflat | O] @ Wo^T + bo  (8192x1024)x(1024x512), bf16 MFMA.
// 64x128 tile/block -> 512 blocks (2/CU).  2x2 waves of (32m x 64n).
// DOUBLE-BUFFERED A/B staging: one barrier per K-slab.
// ---------------------------------------------------------------------------
__global__ __launch_bounds__(256) void out_kernel(
    const u16* __restrict__ Qb, const u16* __restrict__ Ob,
    const u16* __restrict__ Wb, const float* __restrict__ bo,
    float* __restrict__ out)
{
    __shared__ __align__(16) u16 As[2][64][72];    // [buf][m][k]
    __shared__ __align__(16) u16 Bs[2][128][72];   // [buf][n=e][k=j]

    const int t = threadIdx.x, lane = t & 63, w = t >> 6;
    const int e0 = (blockIdx.x & 3) * 128;
    const int n0 = (blockIdx.x >> 2) * 64;
    const int wr = (w >> 1) * 32, wc = (w & 1) * 64;
    const int nl = lane & 15, kg = (lane >> 4) * 8;

    // staging coords
    const int rA = t & 63, cA = (t >> 6) * 8;        // A: 2 vectors (cA, cA+32)
    const int rB = t & 127, cB0 = (t >> 7) * 8;      // B: 4 vectors (cB0,+16,+32,+48)
    const u16* wrow = &Wb[(size_t)(e0 + rB) * 1024];

    floatx4 acc[2][4];
#pragma unroll
    for (int i = 0; i < 2; ++i)
#pragma unroll
        for (int jq = 0; jq < 4; ++jq) acc[i][jq] = 0.f;

    auto a_src = [&](int j0, int r, int c) -> const u16* {
        const int n = n0 + r;
        return (j0 < 512)
            ? &Qb[(((size_t)(n >> 9) * 8 + (j0 >> 6)) * 512 + (n & 511)) * 64 + c]
            : &Ob[(size_t)n * 512 + (j0 - 512) + c];
    };

    // load slab 0 and write into buf 0
    {
        short8 aA = ld8(a_src(0, rA, cA));
        short8 aB = ld8(a_src(0, rA, cA + 32));
        short8 b0 = ld8(wrow + cB0);
        short8 b1 = ld8(wrow + cB0 + 16);
        short8 b2 = ld8(wrow + cB0 + 32);
        short8 b3 = ld8(wrow + cB0 + 48);
        *(short8*)&As[0][rA][cA] = aA;
        *(short8*)&As[0][rA][cA + 32] = aB;
        *(short8*)&Bs[0][rB][cB0] = b0;
        *(short8*)&Bs[0][rB][cB0 + 16] = b1;
        *(short8*)&Bs[0][rB][cB0 + 32] = b2;
        *(short8*)&Bs[0][rB][cB0 + 48] = b3;
    }

    for (int sl = 0; sl < 16; ++sl) {
        const int cur = sl & 1, nxt = cur ^ 1;
        const int j0 = sl * 64;
        short8 aA, aB, b0, b1, b2, b3;
        if (sl < 15) {
            const int jn = j0 + 64;
            aA = ld8(a_src(jn, rA, cA));
            aB = ld8(a_src(jn, rA, cA + 32));
            b0 = ld8(wrow + jn + cB0);
            b1 = ld8(wrow + jn + cB0 + 16);
            b2 = ld8(wrow + jn + cB0 + 32);
            b3 = ld8(wrow + jn + cB0 + 48);
        }
        __syncthreads();    // buf[cur] fully written

        short8 af[2][2], bfr[4][2];
#pragma unroll
        for (int mt = 0; mt < 2; ++mt) {
            af[mt][0] = ld8(&As[cur][wr + mt * 16 + nl][kg]);
            af[mt][1] = ld8(&As[cur][wr + mt * 16 + nl][kg + 32]);
        }
#pragma unroll
        for (int nt = 0; nt < 4; ++nt) {
            bfr[nt][0] = ld8(&Bs[cur][wc + nt * 16 + nl][kg]);
            bfr[nt][1] = ld8(&Bs[cur][wc + nt * 16 + nl][kg + 32]);
        }
#pragma unroll
        for (int mt = 0; mt < 2; ++mt)
#pragma unroll
            for (int nt = 0; nt < 4; ++nt) {
                acc[mt][nt] = __builtin_amdgcn_mfma_f32_16x16x32_bf16(af[mt][0], bfr[nt][0], acc[mt][nt], 0, 0, 0);
                acc[mt][nt] = __builtin_amdgcn_mfma_f32_16x16x32_bf16(af[mt][1], bfr[nt][1], acc[mt][nt], 0, 0, 0);
            }

        if (sl < 15) {
            *(short8*)&As[nxt][rA][cA] = aA;
            *(short8*)&As[nxt][rA][cA + 32] = aB;
            *(short8*)&Bs[nxt][rB][cB0] = b0;
            *(short8*)&Bs[nxt][rB][cB0 + 16] = b1;
            *(short8*)&Bs[nxt][rB][cB0 + 32] = b2;
            *(short8*)&Bs[nxt][rB][cB0 + 48] = b3;
        }
    }

    const int prow = (lane >> 4) * 4;
#pragma unroll
    for (int mt = 0; mt < 2; ++mt)
#pragma unroll
        for (int r = 0; r < 4; ++r) {
            const int n = n0 + wr + mt * 16 + prow + r;
#pragma unroll
            for (int nt = 0; nt < 4; ++nt) {
                const int e = e0 + wc + nt * 16 + nl;
                out[(size_t)n * 512 + e] = acc[mt][nt][r] + bo[e];
            }
        }
}

// ---------------------------------------------------------------------------
extern "C" void kernel_launch(void* const* d_in, const int* in_sizes, int n_in,
                              void* d_out, int out_size, void* d_ws, size_t ws_size,
                              hipStream_t stream)
{
    const float* q_in  = (const float*)d_in[0];
    const float* k_in  = (const float*)d_in[1];
    const float* v_in  = (const float*)d_in[2];
    // d_in[3] = mask (int32) — semantic no-op in the reference
    const float* Wq_in = (const float*)d_in[4];
    const float* bq_in = (const float*)d_in[5];
    const float* Wk_in = (const float*)d_in[6];
    const float* bk_in = (const float*)d_in[7];
    const float* Wv_in = (const float*)d_in[8];
    const float* bv_in = (const float*)d_in[9];
    const float* wvq   = (const float*)d_in[10];
    const float* wvk   = (const float*)d_in[11];
    const float* wvv   = (const float*)d_in[12];
    const float* Wq    = (const float*)d_in[13];
    const float* bq    = (const float*)d_in[14];
    const float* Wk    = (const float*)d_in[15];
    const float* bk    = (const float*)d_in[16];
    const float* Wv    = (const float*)d_in[17];
    const float* bv    = (const float*)d_in[18];
    const float* Wo    = (const float*)d_in[19];
    const float* bo    = (const float*)d_in[20];

    u16* ws = (u16*)d_ws;
    u16* Qb = ws;                          // (B,H,S,D) bf16, 4M elems
    u16* Kb = ws + (size_t)(1 << 22);
    u16* Vb = ws + (size_t)(2 << 22);
    u16* Ob = ws + (size_t)3 * (1 << 22);  // (B,S,E) bf16
    u16* Wb = ws + (size_t)4 * (1 << 22);  // Wo bf16, 512K elems

    proj_kernel<<<PROJ_ROW_BLOCKS + 256, 256, 0, stream>>>(q_in, k_in, v_in,
        Wq_in, bq_in, Wk_in, bk_in, Wv_in, bv_in,
        wvq, wvk, wvv, Wq, bq, Wk, bk, Wv, bv,
        Wo, Wb, Qb, Kb, Vb);
    attn_kernel<<<1024, 256, 0, stream>>>(Qb, Kb, Vb, Ob);
    out_kernel<<<512, 256, 0, stream>>>(Qb, Ob, Wb, bo, (float*)d_out);
}

// Round 9
// 185.981 us; speedup vs baseline: 1.0403x; 1.0403x over previous
//
#include <hip/hip_runtime.h>
#include <hip/hip_bf16.h>

#define B_ 16
#define S_ 512
#define E_ 512
#define H_ 8
#define D_ 64

typedef __hip_bfloat16 bf16;
typedef unsigned short u16;
typedef __attribute__((ext_vector_type(8))) short short8;
typedef __attribute__((ext_vector_type(4))) float floatx4;

__device__ __forceinline__ u16 f2b(float x) {
    bf16 h = __float2bfloat16(x);
    return *reinterpret_cast<u16*>(&h);
}
__device__ __forceinline__ short8 ld8(const u16* p) { return *(const short8*)p; }

// quad_perm DPP xor within groups of 4 lanes (pure VALU, no LDS)
template<int CTRL>
__device__ __forceinline__ float qperm(float x) {
    return __builtin_bit_cast(float,
        __builtin_amdgcn_update_dpp(0, __builtin_bit_cast(int, x), CTRL, 0xF, 0xF, true));
}

#define PROJ_ROW_BLOCKS 3072   // 3 proj x 65536 rows / 64 rows-per-block

// ---------------------------------------------------------------------------
// Kernel A: quantum projections (closed-form VQC), quad-per-row layout.
// 4 lanes own one (b,s,h) row; lane j handles d in [16j,16j+16).
// Q/K/V written bf16 in (B,H,S,D).  Tail blocks convert Wo fp32->bf16.
// ---------------------------------------------------------------------------
__global__ __launch_bounds__(256) void proj_kernel(
    const float* __restrict__ q_in, const float* __restrict__ k_in, const float* __restrict__ v_in,
    const float* __restrict__ Wq_in, const float* __restrict__ bq_in,
    const float* __restrict__ Wk_in, const float* __restrict__ bk_in,
    const float* __restrict__ Wv_in, const float* __restrict__ bv_in,
    const float* __restrict__ wvq, const float* __restrict__ wvk, const float* __restrict__ wvv,
    const float* __restrict__ Wq, const float* __restrict__ bq,
    const float* __restrict__ Wk, const float* __restrict__ bk,
    const float* __restrict__ Wv, const float* __restrict__ bv,
    const float* __restrict__ Wo, u16* __restrict__ Wb,
    u16* __restrict__ Qb, u16* __restrict__ Kb, u16* __restrict__ Vb)
{
    if (blockIdx.x >= PROJ_ROW_BLOCKS) {
        // fused Wo fp32 -> bf16 (524288 elems, 256 blocks x 256 threads x 8)
        const int i = ((blockIdx.x - PROJ_ROW_BLOCKS) * 256 + threadIdx.x) * 8;
        const float4 a = *(const float4*)&Wo[i];
        const float4 b4 = *(const float4*)&Wo[i + 4];
        u16 tmp[8] __attribute__((aligned(16)));
        tmp[0] = f2b(a.x); tmp[1] = f2b(a.y); tmp[2] = f2b(a.z); tmp[3] = f2b(a.w);
        tmp[4] = f2b(b4.x); tmp[5] = f2b(b4.y); tmp[6] = f2b(b4.z); tmp[7] = f2b(b4.w);
        *(short8*)&Wb[i] = *(short8*)tmp;
        return;
    }

    __shared__ __align__(16) float sWin[256];    // [q][d]  (4 x 64)
    __shared__ __align__(16) float sWout[256];   // [d][q]  (64 x 4)
    __shared__ __align__(16) float sbout[64];
    __shared__ float4 sbw;                       // bin + wv (aligned)

    const int t = threadIdx.x;
    const int p = blockIdx.x >> 10;           // projection 0/1/2

    const float *X, *Win, *bin, *wv, *Wout, *bout;
    u16* dst;
    if (p == 0)      { X = q_in; Win = Wq_in; bin = bq_in; wv = wvq; Wout = Wq; bout = bq; dst = Qb; }
    else if (p == 1) { X = k_in; Win = Wk_in; bin = bk_in; wv = wvk; Wout = Wk; bout = bk; dst = Kb; }
    else             { X = v_in; Win = Wv_in; bin = bv_in; wv = wvv; Wout = Wv; bout = bv; dst = Vb; }

    sWin[t] = Win[t];
    sWout[t] = Wout[t];
    if (t < 64) sbout[t] = bout[t];
    if (t == 0) sbw = make_float4(bin[0] + wv[0], bin[1] + wv[1],
                                  bin[2] + wv[2], bin[3] + wv[3]);
    __syncthreads();

    const int j = t & 3;                       // d-quarter within row
    const int m = (blockIdx.x & 1023) * 64 + (t >> 2);   // row = b*4096 + s*8 + h
    const int d0 = j * 16;

    // ---- dot phase: part[q] over my 16 d's, then quad reduce via DPP
    const float* xp = X + (size_t)m * 64 + d0;
    float4 xv[4];
#pragma unroll
    for (int i = 0; i < 4; ++i) xv[i] = *(const float4*)(xp + i * 4);

    float part[4] = {0.f, 0.f, 0.f, 0.f};
#pragma unroll
    for (int i = 0; i < 4; ++i) {
#pragma unroll
        for (int q = 0; q < 4; ++q) {
            const float4 w4 = *(const float4*)&sWin[q * 64 + d0 + i * 4];
            part[q] = fmaf(xv[i].x, w4.x, fmaf(xv[i].y, w4.y,
                      fmaf(xv[i].z, w4.z, fmaf(xv[i].w, w4.w, part[q]))));
        }
    }
#pragma unroll
    for (int q = 0; q < 4; ++q) {
        part[q] += qperm<0xB1>(part[q]);   // xor 1
        part[q] += qperm<0x4E>(part[q]);   // xor 2
    }

    const float4 bw = sbw;
    const float c0 = __cosf(part[0] + bw.x);
    const float c1 = __cosf(part[1] + bw.y);
    const float c2 = __cosf(part[2] + bw.z);
    const float c3 = __cosf(part[3] + bw.w);
    const float tt = c2 * c3;
    const float z1 = c0 * c1;
    const float z0 = c1 * tt;
    const float z2 = z1 * c2;
    const float z3 = z1 * tt;

    // ---- output phase: my 16 d's
    const int b = m >> 12, s = (m >> 3) & 511, h = m & 7;
    u16* op = dst + ((size_t)(b * 4096 + h * 512 + s)) * 64 + d0;

    u16 tmp[16] __attribute__((aligned(16)));
#pragma unroll
    for (int d = 0; d < 16; ++d) {
        const float4 wo = *(const float4*)&sWout[(d0 + d) * 4];
        const float o = fmaf(z0, wo.x, fmaf(z1, wo.y,
                        fmaf(z2, wo.z, fmaf(z3, wo.w, sbout[d0 + d]))));
        tmp[d] = f2b(o);
    }
    *(short8*)op = *(short8*)tmp;
    *(short8*)(op + 8) = *(short8*)(tmp + 8);
}

// ---------------------------------------------------------------------------
// Kernel B: flash MFMA attention, NO max-tracking (softmax arg = S/32, tiny).
// Block = 128 q-rows of one (b,h); 4 waves x 32 rows (2 Q-frags/wave) so each
// staged K/V fragment feeds TWO MFMAs (DS reads/MFMA: 1.125 -> 0.625).
// 8 chunks of 64 k-pos; single-buffer staging + register prefetch (r7 form).
// ---------------------------------------------------------------------------
__global__ __launch_bounds__(256) void attn_kernel(
    const u16* __restrict__ Qb, const u16* __restrict__ Kb, const u16* __restrict__ Vb,
    u16* __restrict__ Ob)
{
    __shared__ __align__(16) u16 Ks[64][72];        // [kpos][d]
    __shared__ __align__(16) u16 Vt[64][72];        // [d][kpos] (transposed)
    __shared__ __align__(16) u16 Ps[4][32][72];     // per-wave P [qrow][kpos]

    const int t = threadIdx.x, lane = t & 63, w = t >> 6;
    const int bh = blockIdx.x >> 2;
    const int q0 = (blockIdx.x & 3) * 128;
    const int b = bh >> 3, h = bh & 7;

    const u16* Qp = Qb + (size_t)bh * (S_ * D_) + (size_t)q0 * D_;
    const u16* Kp = Kb + (size_t)bh * (S_ * D_);
    const u16* Vp = Vb + (size_t)bh * (S_ * D_);

    const int nl = lane & 15;           // n-index within 16x16 tile
    const int kg = (lane >> 4) * 8;     // k-group offset

    // 2 Q fragments per wave straight from global (coalesced 16B)
    short8 qa[2][2];
#pragma unroll
    for (int mt = 0; mt < 2; ++mt) {
        qa[mt][0] = ld8(&Qp[(w * 32 + mt * 16 + nl) * 64 + kg]);
        qa[mt][1] = ld8(&Qp[(w * 32 + mt * 16 + nl) * 64 + kg + 32]);
    }

    floatx4 of[2][4];
    float l_run[2][4];
#pragma unroll
    for (int mt = 0; mt < 2; ++mt)
#pragma unroll
        for (int r = 0; r < 4; ++r) { l_run[mt][r] = 0.f; }
#pragma unroll
    for (int mt = 0; mt < 2; ++mt)
#pragma unroll
        for (int nt = 0; nt < 4; ++nt) of[mt][nt] = 0.f;

    // staging coords
    const int rK = t & 63, cK = (t >> 6) * 8;            // K: 2 vectors (cK, cK+32)
    const int vr0 = (t & 31) * 2, vc = (t >> 5) * 8;     // V: rows vr0, vr0+1 at col vc

    // prefetch chunk 0
    short8 kA = ld8(&Kp[rK * 64 + cK]);
    short8 kB = ld8(&Kp[rK * 64 + cK + 32]);
    short8 vA = ld8(&Vp[vr0 * 64 + vc]);
    short8 vB = ld8(&Vp[(vr0 + 1) * 64 + vc]);

    for (int ch = 0; ch < 8; ++ch) {
        __syncthreads();
        // write staged chunk to LDS
        *(short8*)&Ks[rK][cK] = kA;
        *(short8*)&Ks[rK][cK + 32] = kB;
#pragma unroll
        for (int jj = 0; jj < 8; ++jj) {
            const unsigned pack = (u16)((short*)&vA)[jj] |
                                  ((unsigned)(u16)((short*)&vB)[jj] << 16);
            *(unsigned*)&Vt[vc + jj][vr0] = pack;
        }
        // prefetch next chunk (latency hidden behind this chunk's compute)
        if (ch < 7) {
            const int nb = (ch + 1) * 64;
            kA = ld8(&Kp[(nb + rK) * 64 + cK]);
            kB = ld8(&Kp[(nb + rK) * 64 + cK + 32]);
            vA = ld8(&Vp[(nb + vr0) * 64 + vc]);
            vB = ld8(&Vp[(nb + vr0 + 1) * 64 + vc]);
        }
        __syncthreads();

        // S = Q K^T  (each K fragment feeds both Q fragments)
        floatx4 sf[2][4];
#pragma unroll
        for (int mt = 0; mt < 2; ++mt)
#pragma unroll
            for (int nt = 0; nt < 4; ++nt) sf[mt][nt] = 0.f;
#pragma unroll
        for (int nt = 0; nt < 4; ++nt) {
            const short8 kf0 = ld8(&Ks[nt * 16 + nl][kg]);
            const short8 kf1 = ld8(&Ks[nt * 16 + nl][kg + 32]);
#pragma unroll
            for (int mt = 0; mt < 2; ++mt) {
                sf[mt][nt] = __builtin_amdgcn_mfma_f32_16x16x32_bf16(qa[mt][0], kf0, sf[mt][nt], 0, 0, 0);
                sf[mt][nt] = __builtin_amdgcn_mfma_f32_16x16x32_bf16(qa[mt][1], kf1, sf[mt][nt], 0, 0, 0);
            }
        }

        // P = exp(S/32), accumulate row-sum partials in registers
        const int prow = (lane >> 4) * 4;
#pragma unroll
        for (int mt = 0; mt < 2; ++mt)
#pragma unroll
            for (int nt = 0; nt < 4; ++nt) {
#pragma unroll
                for (int r = 0; r < 4; ++r) {
                    const float pv = __expf(sf[mt][nt][r] * 0.03125f);
                    l_run[mt][r] += pv;
                    Ps[w][mt * 16 + prow + r][nt * 16 + nl] = f2b(pv);
                }
            }

        // O += P V (same-wave LDS round-trip; V fragment feeds both P frags)
        short8 pa[2][2];
#pragma unroll
        for (int mt = 0; mt < 2; ++mt) {
            pa[mt][0] = ld8(&Ps[w][mt * 16 + nl][kg]);
            pa[mt][1] = ld8(&Ps[w][mt * 16 + nl][kg + 32]);
        }
#pragma unroll
        for (int nt = 0; nt < 4; ++nt) {
            const short8 vf0 = ld8(&Vt[nt * 16 + nl][kg]);
            const short8 vf1 = ld8(&Vt[nt * 16 + nl][kg + 32]);
#pragma unroll
            for (int mt = 0; mt < 2; ++mt) {
                of[mt][nt] = __builtin_amdgcn_mfma_f32_16x16x32_bf16(pa[mt][0], vf0, of[mt][nt], 0, 0, 0);
                of[mt][nt] = __builtin_amdgcn_mfma_f32_16x16x32_bf16(pa[mt][1], vf1, of[mt][nt], 0, 0, 0);
            }
        }
    }

    // final row-sum reduce (16 lanes share a row) + store O/l bf16 to (B,S,E)
#pragma unroll
    for (int mt = 0; mt < 2; ++mt) {
        float inv[4];
#pragma unroll
        for (int r = 0; r < 4; ++r) {
            float sum = l_run[mt][r];
#pragma unroll
            for (int off = 1; off < 16; off <<= 1) sum += __shfl_xor(sum, off, 64);
            inv[r] = 1.0f / sum;
        }
        const int srow = q0 + w * 32 + mt * 16 + (lane >> 4) * 4;
#pragma unroll
        for (int r = 0; r < 4; ++r) {
            const size_t base = ((size_t)(b * S_ + srow + r)) * E_ + h * 64 + nl;
#pragma unroll
            for (int nt = 0; nt < 4; ++nt)
                Ob[base + nt * 16] = f2b(of[mt][nt][r] * inv[r]);
        }
    }
}

// ---------------------------------------------------------------------------
// Kernel C: out = [Qflat | O] @ Wo^T + bo  (8192x1024)x(1024x512), bf16 MFMA.
// 64x128 tile/block -> 512 blocks (2/CU).  2x2 waves of (32m x 64n).
// Next K-slab's global loads prefetched into regs (r7 single-buffer form).
// ---------------------------------------------------------------------------
__global__ __launch_bounds__(256) void out_kernel(
    const u16* __restrict__ Qb, const u16* __restrict__ Ob,
    const u16* __restrict__ Wb, const float* __restrict__ bo,
    float* __restrict__ out)
{
    __shared__ __align__(16) u16 As[64][72];    // cat rows [m][k]
    __shared__ __align__(16) u16 Bs[128][72];   // Wo rows  [n=e][k=j]

    const int t = threadIdx.x, lane = t & 63, w = t >> 6;
    const int e0 = (blockIdx.x & 3) * 128;
    const int n0 = (blockIdx.x >> 2) * 64;
    const int wr = (w >> 1) * 32, wc = (w & 1) * 64;
    const int nl = lane & 15, kg = (lane >> 4) * 8;

    // staging coords
    const int rA = t & 63, cA = (t >> 6) * 8;        // A: 2 vectors (cA, cA+32)
    const int rB = t & 127, cB0 = (t >> 7) * 8;      // B: 4 vectors (cB0,+16,+32,+48)
    const u16* wrow = &Wb[(size_t)(e0 + rB) * 1024];

    floatx4 acc[2][4];
#pragma unroll
    for (int i = 0; i < 2; ++i)
#pragma unroll
        for (int jq = 0; jq < 4; ++jq) acc[i][jq] = 0.f;

    auto a_src = [&](int j0, int r, int c) -> const u16* {
        const int n = n0 + r;
        return (j0 < 512)
            ? &Qb[(((size_t)(n >> 9) * 8 + (j0 >> 6)) * 512 + (n & 511)) * 64 + c]
            : &Ob[(size_t)n * 512 + (j0 - 512) + c];
    };

    // prefetch slab 0
    short8 aA = ld8(a_src(0, rA, cA));
    short8 aB = ld8(a_src(0, rA, cA + 32));
    short8 b0 = ld8(wrow + cB0);
    short8 b1 = ld8(wrow + cB0 + 16);
    short8 b2 = ld8(wrow + cB0 + 32);
    short8 b3 = ld8(wrow + cB0 + 48);

    for (int j0 = 0; j0 < 1024; j0 += 64) {
        __syncthreads();
        *(short8*)&As[rA][cA] = aA;
        *(short8*)&As[rA][cA + 32] = aB;
        *(short8*)&Bs[rB][cB0] = b0;
        *(short8*)&Bs[rB][cB0 + 16] = b1;
        *(short8*)&Bs[rB][cB0 + 32] = b2;
        *(short8*)&Bs[rB][cB0 + 48] = b3;
        if (j0 < 960) {
            const int jn = j0 + 64;
            aA = ld8(a_src(jn, rA, cA));
            aB = ld8(a_src(jn, rA, cA + 32));
            b0 = ld8(wrow + jn + cB0);
            b1 = ld8(wrow + jn + cB0 + 16);
            b2 = ld8(wrow + jn + cB0 + 32);
            b3 = ld8(wrow + jn + cB0 + 48);
        }
        __syncthreads();

        short8 af[2][2], bfr[4][2];
#pragma unroll
        for (int mt = 0; mt < 2; ++mt) {
            af[mt][0] = ld8(&As[wr + mt * 16 + nl][kg]);
            af[mt][1] = ld8(&As[wr + mt * 16 + nl][kg + 32]);
        }
#pragma unroll
        for (int nt = 0; nt < 4; ++nt) {
            bfr[nt][0] = ld8(&Bs[wc + nt * 16 + nl][kg]);
            bfr[nt][1] = ld8(&Bs[wc + nt * 16 + nl][kg + 32]);
        }
#pragma unroll
        for (int mt = 0; mt < 2; ++mt)
#pragma unroll
            for (int nt = 0; nt < 4; ++nt) {
                acc[mt][nt] = __builtin_amdgcn_mfma_f32_16x16x32_bf16(af[mt][0], bfr[nt][0], acc[mt][nt], 0, 0, 0);
                acc[mt][nt] = __builtin_amdgcn_mfma_f32_16x16x32_bf16(af[mt][1], bfr[nt][1], acc[mt][nt], 0, 0, 0);
            }
    }

    const int prow = (lane >> 4) * 4;
#pragma unroll
    for (int mt = 0; mt < 2; ++mt)
#pragma unroll
        for (int r = 0; r < 4; ++r) {
            const int n = n0 + wr + mt * 16 + prow + r;
#pragma unroll
            for (int nt = 0; nt < 4; ++nt) {
                const int e = e0 + wc + nt * 16 + nl;
                out[(size_t)n * 512 + e] = acc[mt][nt][r] + bo[e];
            }
        }
}

// ---------------------------------------------------------------------------
extern "C" void kernel_launch(void* const* d_in, const int* in_sizes, int n_in,
                              void* d_out, int out_size, void* d_ws, size_t ws_size,
                              hipStream_t stream)
{
    const float* q_in  = (const float*)d_in[0];
    const float* k_in  = (const float*)d_in[1];
    const float* v_in  = (const float*)d_in[2];
    // d_in[3] = mask (int32) — semantic no-op in the reference
    const float* Wq_in = (const float*)d_in[4];
    const float* bq_in = (const float*)d_in[5];
    const float* Wk_in = (const float*)d_in[6];
    const float* bk_in = (const float*)d_in[7];
    const float* Wv_in = (const float*)d_in[8];
    const float* bv_in = (const float*)d_in[9];
    const float* wvq   = (const float*)d_in[10];
    const float* wvk   = (const float*)d_in[11];
    const float* wvv   = (const float*)d_in[12];
    const float* Wq    = (const float*)d_in[13];
    const float* bq    = (const float*)d_in[14];
    const float* Wk    = (const float*)d_in[15];
    const float* bk    = (const float*)d_in[16];
    const float* Wv    = (const float*)d_in[17];
    const float* bv    = (const float*)d_in[18];
    const float* Wo    = (const float*)d_in[19];
    const float* bo    = (const float*)d_in[20];

    u16* ws = (u16*)d_ws;
    u16* Qb = ws;                          // (B,H,S,D) bf16, 4M elems
    u16* Kb = ws + (size_t)(1 << 22);
    u16* Vb = ws + (size_t)(2 << 22);
    u16* Ob = ws + (size_t)3 * (1 << 22);  // (B,S,E) bf16
    u16* Wb = ws + (size_t)4 * (1 << 22);  // Wo bf16, 512K elems

    proj_kernel<<<PROJ_ROW_BLOCKS + 256, 256, 0, stream>>>(q_in, k_in, v_in,
        Wq_in, bq_in, Wk_in, bk_in, Wv_in, bv_in,
        wvq, wvk, wvv, Wq, bq, Wk, bk, Wv, bv,
        Wo, Wb, Qb, Kb, Vb);
    attn_kernel<<<512, 256, 0, stream>>>(Qb, Kb, Vb, Ob);
    out_kernel<<<512, 256, 0, stream>>>(Qb, Ob, Wb, bo, (float*)d_out);
}